// Round 10
// baseline (69.517 us; speedup 1.0000x reference)
//
#include <hip/hip_runtime.h>
#include <hip/hip_bf16.h>

#define BATCH 65536
#define INF   64
#define OUTF  256
#define NMAT  15
#define RPB   256          // rows per block
#define NST   4            // super-tiles of 64 rows

typedef __bf16 bf16x8 __attribute__((ext_vector_type(8)));
typedef float  f32x4  __attribute__((ext_vector_type(4)));

__device__ __forceinline__ unsigned short f2bf(float f) {
    unsigned int u = __float_as_uint(f);
    unsigned int r = (u + 0x7FFFu + ((u >> 16) & 1u)) >> 16;
    return (unsigned short)r;
}

// ---------------------------------------------------------------------------
// Swizzled layouts (fragment-contiguous; every wave memory op = 1 KB contig):
//   xs:  per 16-row group grp: byte = grp*2048 + s*1024 + lane*16
//        (lane = g*16 + r, r = row&15, k = s*32 + g*8 + j)
//   wcs: per (mat w, 16-col strip cs): byte = ((w*16+cs)*2+s)*1024 + lane*16
// ---------------------------------------------------------------------------
__global__ void prep(const float* __restrict__ x,
                     const float* __restrict__ d1t_w,
                     const float* __restrict__ d1_w,
                     const float* __restrict__ dn_w1,
                     const float* __restrict__ dn_w2,
                     unsigned short* __restrict__ wcs,
                     unsigned short* __restrict__ xs) {
    const int idx = blockIdx.x * 256 + threadIdx.x;   // one 16-B chunk each

    {   // x: chunk idx covers row = idx>>3, elems cc*8..cc*8+7
        const int row = idx >> 3, cc = idx & 7;
        const int s = cc >> 2, g = cc & 3;
        const int grp = row >> 4, r = row & 15;
        const float* xp = x + (size_t)row * INF + cc * 8;
        f32x4 v0 = *(const f32x4*)xp;
        f32x4 v1 = *(const f32x4*)(xp + 4);
        bf16x8 fr;
#pragma unroll
        for (int j = 0; j < 4; ++j) { fr[j] = (__bf16)v0[j]; fr[4 + j] = (__bf16)v1[j]; }
        *(bf16x8*)((char*)xs + (size_t)grp * 2048 + s * 1024 + g * 256 + r * 16) = fr;
    }

    if (idx < NMAT * OUTF * INF / 8) {
        const signed char kind[NMAT] = {0,1,2,1,2,2,1,2,2,2,1,2,2,2,2};
        const signed char sidx[NMAT] = {0,0,0,1,1,2,2,3,4,5,3,6,7,8,9};
        const int slot = idx >> 11, rem8 = idx & 2047;
        const int o = rem8 >> 3, cc = rem8 & 7;
        const int s = cc >> 2, g = cc & 3;
        const int i0 = cc * 8;
        const int cs = o >> 4, l = o & 15;
        const int k = kind[slot], si = sidx[slot];
        unsigned short o8[8];
#pragma unroll
        for (int j = 0; j < 8; ++j) {
            const int e = o * INF + i0 + j;
            float v;
            if (k == 0)      v = d1t_w[e];
            else if (k == 1) v = d1_w[si * OUTF * INF + e];
            else             v = dn_w2[si * OUTF * INF + e] * dn_w1[si * INF + i0 + j];
            o8[j] = f2bf(v);
        }
        char* dst = (char*)wcs + (((size_t)slot * 16 + cs) * 2 + s) * 1024 + g * 256 + l * 16;
        *(bf16x8*)dst = *(bf16x8*)o8;
    }
}

// One 64-row super-tile: 4 row-groups x 2 k-halves, named members (no scratch).
struct ST { bf16x8 f0, f1, f2, f3, f4, f5, f6, f7; };

#define LDS_W 68   // 64 cols + 4 pad

__global__ __launch_bounds__(256) void taylor_kernel(
    const unsigned short* __restrict__ xs, const float* __restrict__ d0,
    const unsigned short* __restrict__ wcs, float* __restrict__ out)
{
    __shared__ float sbuf[2][64 * LDS_W];   // 34.8 KB, double-buffered

    const int lane = threadIdx.x & 63;
    const int wave = threadIdx.x >> 6;      // 0..3
    const int l15  = lane & 15;
    const int g    = lane >> 4;
    // sharers of one row-chunk: bids {rc, rc+256, rc+512, rc+768} -> same XCD
    const int cg   = blockIdx.x >> 8;       // col-group (64 cols)
    const int rc   = blockIdx.x & 255;      // row-chunk (RPB rows)
    const int cs   = cg * 4 + wave;         // 16-col strip id
    const int colstrip = cs * 16;

    // Weight prologue: 30 contiguous 1-KB loads.
    bf16x8 b[NMAT][2];
    const char* wbase = (const char*)wcs + (size_t)cs * 2048 + lane * 16;
#pragma unroll
    for (int w = 0; w < NMAT; ++w)
#pragma unroll
        for (int s = 0; s < 2; ++s)
            b[w][s] = *(const bf16x8*)(wbase + (size_t)w * 32768 + s * 1024);

    const f32x4 d0v = *(const f32x4*)(d0 + colstrip + g * 4);

    constexpr int OPS[NMAT] = {0,1,3,1,2,3,1,2,2,3,1,2,2,2,3};
    const size_t row0 = (size_t)rc * RPB;
    const char* xbase = (const char*)xs + (row0 >> 4) * 2048 + lane * 16;

    auto issue = [&](ST& T_, int T) {   // 8 contiguous 1-KB loads (one super-tile)
        const char* p = xbase + (size_t)T * 8192;
        T_.f0 = *(const bf16x8*)(p);
        T_.f1 = *(const bf16x8*)(p + 1024);
        T_.f2 = *(const bf16x8*)(p + 2048);
        T_.f3 = *(const bf16x8*)(p + 3072);
        T_.f4 = *(const bf16x8*)(p + 4096);
        T_.f5 = *(const bf16x8*)(p + 5120);
        T_.f6 = *(const bf16x8*)(p + 6144);
        T_.f7 = *(const bf16x8*)(p + 7168);
    };

    auto cstore = [&](const ST& U, int T) {
        // 4 independent MFMA->VALU streams (one per 16-row group)
        f32x4 res0, res1, res2, res3, tmp0, tmp1, tmp2, tmp3;
#pragma unroll
        for (int w = 0; w < NMAT; ++w) {
            f32x4 c0 = (OPS[w] == 0) ? d0v : f32x4{0.f, 0.f, 0.f, 0.f};
            f32x4 y0 = __builtin_amdgcn_mfma_f32_16x16x32_bf16(b[w][0], U.f0, c0, 0, 0, 0);
            f32x4 y1 = __builtin_amdgcn_mfma_f32_16x16x32_bf16(b[w][0], U.f2, c0, 0, 0, 0);
            f32x4 y2 = __builtin_amdgcn_mfma_f32_16x16x32_bf16(b[w][0], U.f4, c0, 0, 0, 0);
            f32x4 y3 = __builtin_amdgcn_mfma_f32_16x16x32_bf16(b[w][0], U.f6, c0, 0, 0, 0);
            y0 = __builtin_amdgcn_mfma_f32_16x16x32_bf16(b[w][1], U.f1, y0, 0, 0, 0);
            y1 = __builtin_amdgcn_mfma_f32_16x16x32_bf16(b[w][1], U.f3, y1, 0, 0, 0);
            y2 = __builtin_amdgcn_mfma_f32_16x16x32_bf16(b[w][1], U.f5, y2, 0, 0, 0);
            y3 = __builtin_amdgcn_mfma_f32_16x16x32_bf16(b[w][1], U.f7, y3, 0, 0, 0);
            if (OPS[w] == 0)      { res0 = y0; res1 = y1; res2 = y2; res3 = y3; }
            else if (OPS[w] == 1) { tmp0 = y0; tmp1 = y1; tmp2 = y2; tmp3 = y3; }
            else {
                tmp0 = tmp0 * y0; tmp1 = tmp1 * y1; tmp2 = tmp2 * y2; tmp3 = tmp3 * y3;
                if (OPS[w] == 3) { res0 = res0 + tmp0; res1 = res1 + tmp1;
                                   res2 = res2 + tmp2; res3 = res3 + tmp3; }
            }
        }
        // LDS transpose (double-buffered -> one barrier per super-tile)
        float* sb = sbuf[T & 1];
        const int colw = wave * 16 + g * 4;
        *(f32x4*)&sb[(l15)      * LDS_W + colw] = res0;
        *(f32x4*)&sb[(16 + l15) * LDS_W + colw] = res1;
        *(f32x4*)&sb[(32 + l15) * LDS_W + colw] = res2;
        *(f32x4*)&sb[(48 + l15) * LDS_W + colw] = res3;
        __syncthreads();
        // coalesced store: each wave-inst = 4 rows x 256 B (full lines)
        const size_t rbase = row0 + (size_t)T * 64;
#pragma unroll
        for (int j = 0; j < 4; ++j) {
            const int row = wave * 16 + j * 4 + g;
            f32x4 v = *(const f32x4*)&sb[row * LDS_W + l15 * 4];
            *(f32x4*)(out + (rbase + row) * OUTF + cg * 64 + l15 * 4) = v;
        }
    };

    ST A, B;
    issue(A, 0);
    issue(B, 1); cstore(A, 0);
    issue(A, 2); cstore(B, 1);
    issue(B, 3); cstore(A, 2);
    cstore(B, 3);
}

// ---------------- fallback path (ws too small): R6-style fp32 kernel --------
__global__ void build_weights_only(const float* __restrict__ d1t_w,
                                   const float* __restrict__ d1_w,
                                   const float* __restrict__ dn_w1,
                                   const float* __restrict__ dn_w2,
                                   unsigned short* __restrict__ wc) {
    int idx = blockIdx.x * blockDim.x + threadIdx.x;
    if (idx >= NMAT * OUTF * INF) return;
    int slot = idx / (OUTF * INF);
    int rem  = idx - slot * (OUTF * INF);
    int i    = rem & (INF - 1);
    const signed char kind[NMAT] = {0,1,2,1,2,2,1,2,2,2,1,2,2,2,2};
    const signed char sidx[NMAT] = {0,0,0,1,1,2,2,3,4,5,3,6,7,8,9};
    int k = kind[slot], si = sidx[slot];
    float v;
    if (k == 0)      v = d1t_w[rem];
    else if (k == 1) v = d1_w[si * OUTF * INF + rem];
    else             v = dn_w2[si * OUTF * INF + rem] * dn_w1[si * INF + i];
    wc[idx] = f2bf(v);
}

__global__ __launch_bounds__(256) void taylor_f32(
    const float* __restrict__ x, const float* __restrict__ d0,
    const unsigned short* __restrict__ wc, float* __restrict__ out)
{
    const int lane = threadIdx.x & 63;
    const int wave = threadIdx.x >> 6;
    const int l15  = lane & 15;
    const int g    = lane >> 4;
    const int cg   = blockIdx.x & 3;
    const int rc   = blockIdx.x >> 2;
    const int colstrip = cg * 64 + wave * 16;

    bf16x8 b[NMAT][2];
#pragma unroll
    for (int w = 0; w < NMAT; ++w) {
        const unsigned short* wp = wc + ((size_t)w * OUTF + colstrip + l15) * INF + g * 8;
#pragma unroll
        for (int s = 0; s < 2; ++s)
            b[w][s] = *(const bf16x8*)(wp + s * 32);
    }
    const f32x4 d0v = *(const f32x4*)(d0 + colstrip + g * 4);
    constexpr int OPS[NMAT] = {0,1,3,1,2,3,1,2,2,3,1,2,2,2,3};
    const size_t row0 = (size_t)rc * RPB;

#pragma unroll 1
    for (int it = 0; it < RPB / 32; ++it) {
        bf16x8 a00, a01, a10, a11;
        {
            const float* xp0 = x + (row0 + (size_t)it * 32 + l15) * INF + g * 8;
            const float* xp1 = xp0 + 16 * INF;
            f32x4 u0, u1; bf16x8 fr;
#define CVT8(dst, p0) { u0 = *(const f32x4*)(p0); u1 = *(const f32x4*)((p0) + 4); \
            for (int j = 0; j < 4; ++j) { fr[j] = (__bf16)u0[j]; fr[4+j] = (__bf16)u1[j]; } dst = fr; }
            CVT8(a00, xp0); CVT8(a01, xp0 + 32); CVT8(a10, xp1); CVT8(a11, xp1 + 32);
#undef CVT8
        }
        f32x4 res0, res1, tmp0, tmp1;
#pragma unroll
        for (int w = 0; w < NMAT; ++w) {
            f32x4 c0 = (OPS[w] == 0) ? d0v : f32x4{0.f, 0.f, 0.f, 0.f};
            f32x4 y0 = __builtin_amdgcn_mfma_f32_16x16x32_bf16(b[w][0], a00, c0, 0, 0, 0);
            y0       = __builtin_amdgcn_mfma_f32_16x16x32_bf16(b[w][1], a01, y0, 0, 0, 0);
            f32x4 y1 = __builtin_amdgcn_mfma_f32_16x16x32_bf16(b[w][0], a10, c0, 0, 0, 0);
            y1       = __builtin_amdgcn_mfma_f32_16x16x32_bf16(b[w][1], a11, y1, 0, 0, 0);
            if (OPS[w] == 0)      { res0 = y0; res1 = y1; }
            else if (OPS[w] == 1) { tmp0 = y0; tmp1 = y1; }
            else {
                tmp0 = tmp0 * y0; tmp1 = tmp1 * y1;
                if (OPS[w] == 3) { res0 = res0 + tmp0; res1 = res1 + tmp1; }
            }
        }
        const size_t rbase = row0 + (size_t)it * 32;
        *(f32x4*)(out + (rbase + l15) * OUTF + colstrip + g * 4) = res0;
        *(f32x4*)(out + (rbase + 16 + l15) * OUTF + colstrip + g * 4) = res1;
    }
}

extern "C" void kernel_launch(void* const* d_in, const int* in_sizes, int n_in,
                              void* d_out, int out_size, void* d_ws, size_t ws_size,
                              hipStream_t stream) {
    const float* x    = (const float*)d_in[0];
    const float* d0   = (const float*)d_in[1];
    const float* d1t  = (const float*)d_in[2];
    const float* d1w  = (const float*)d_in[3];
    const float* dnw1 = (const float*)d_in[4];
    const float* dnw2 = (const float*)d_in[5];
    unsigned short* wc = (unsigned short*)d_ws;                 // 480 KiB (swizzled)
    float* out = (float*)d_out;

    const size_t XB_OFF   = 512 * 1024;
    const size_t XB_BYTES = (size_t)BATCH * INF * 2;            // 8 MiB
    if (ws_size >= XB_OFF + XB_BYTES) {
        unsigned short* xs = (unsigned short*)((char*)d_ws + XB_OFF);
        prep<<<BATCH * INF / 8 / 256, 256, 0, stream>>>(x, d1t, d1w, dnw1, dnw2, wc, xs);
        taylor_kernel<<<4 * (BATCH / RPB), 256, 0, stream>>>(xs, d0, wc, out);
    } else {
        build_weights_only<<<(NMAT * OUTF * INF + 255) / 256, 256, 0, stream>>>(d1t, d1w, dnw1, dnw2, wc);
        taylor_f32<<<4 * (BATCH / RPB), 256, 0, stream>>>(x, d0, wc, out);
    }
}

// Round 11
// 50.822 us; speedup vs baseline: 1.3679x; 1.3679x over previous
//
#include <hip/hip_runtime.h>
#include <hip/hip_bf16.h>

#define BATCH 65536
#define INF   64
#define OUTF  256
#define NMAT  15
#define RPB   256          // rows per block

typedef __bf16 bf16x8 __attribute__((ext_vector_type(8)));
typedef float  f32x4  __attribute__((ext_vector_type(4)));

__device__ __forceinline__ unsigned short f2bf(float f) {
    unsigned int u = __float_as_uint(f);
    unsigned int r = (u + 0x7FFFu + ((u >> 16) & 1u)) >> 16;
    return (unsigned short)r;
}

// ---------------------------------------------------------------------------
// Swizzled layouts (fragment-contiguous; every wave memory op = 1 KB contig):
//   xs:  per 16-row group grp: byte = grp*2048 + s*1024 + lane*16
//        (lane = g*16 + r, r = row&15, k = s*32 + g*8 + j)
//   wcs: per (mat w, 16-col strip cs): byte = ((w*16+cs)*2+s)*1024 + lane*16
// ---------------------------------------------------------------------------
__global__ void prep(const float* __restrict__ x,
                     const float* __restrict__ d1t_w,
                     const float* __restrict__ d1_w,
                     const float* __restrict__ dn_w1,
                     const float* __restrict__ dn_w2,
                     unsigned short* __restrict__ wcs,
                     unsigned short* __restrict__ xs) {
    const int idx = blockIdx.x * 256 + threadIdx.x;   // one 16-B chunk each

    {   // x: chunk idx covers row = idx>>3, elems cc*8..cc*8+7
        const int row = idx >> 3, cc = idx & 7;
        const int s = cc >> 2, g = cc & 3;
        const int grp = row >> 4, r = row & 15;
        const float* xp = x + (size_t)row * INF + cc * 8;
        f32x4 v0 = *(const f32x4*)xp;
        f32x4 v1 = *(const f32x4*)(xp + 4);
        bf16x8 fr;
#pragma unroll
        for (int j = 0; j < 4; ++j) { fr[j] = (__bf16)v0[j]; fr[4 + j] = (__bf16)v1[j]; }
        *(bf16x8*)((char*)xs + (size_t)grp * 2048 + s * 1024 + g * 256 + r * 16) = fr;
    }

    if (idx < NMAT * OUTF * INF / 8) {
        const signed char kind[NMAT] = {0,1,2,1,2,2,1,2,2,2,1,2,2,2,2};
        const signed char sidx[NMAT] = {0,0,0,1,1,2,2,3,4,5,3,6,7,8,9};
        const int slot = idx >> 11, rem8 = idx & 2047;
        const int o = rem8 >> 3, cc = rem8 & 7;
        const int s = cc >> 2, g = cc & 3;
        const int i0 = cc * 8;
        const int cs = o >> 4, l = o & 15;
        const int k = kind[slot], si = sidx[slot];
        unsigned short o8[8];
#pragma unroll
        for (int j = 0; j < 8; ++j) {
            const int e = o * INF + i0 + j;
            float v;
            if (k == 0)      v = d1t_w[e];
            else if (k == 1) v = d1_w[si * OUTF * INF + e];
            else             v = dn_w2[si * OUTF * INF + e] * dn_w1[si * INF + i0 + j];
            o8[j] = f2bf(v);
        }
        char* dst = (char*)wcs + (((size_t)slot * 16 + cs) * 2 + s) * 1024 + g * 256 + l * 16;
        *(bf16x8*)dst = *(bf16x8*)o8;
    }
}

struct Tile { bf16x8 v00, v01, v10, v11; };   // named members: no scratch demotion

#define LDS_W 68   // 64 cols + 4 pad

__global__ __launch_bounds__(256) void taylor_kernel(
    const unsigned short* __restrict__ xs, const float* __restrict__ d0,
    const unsigned short* __restrict__ wcs, float* __restrict__ out)
{
    __shared__ float sbuf[2][32 * LDS_W];   // 17.4 KB, double-buffered

    const int lane = threadIdx.x & 63;
    const int wave = threadIdx.x >> 6;      // 0..3
    const int l15  = lane & 15;
    const int g    = lane >> 4;
    // sharers of one row-chunk: bids {rc, rc+256, rc+512, rc+768} -> same XCD
    const int cg   = blockIdx.x >> 8;       // col-group (64 cols)
    const int rc   = blockIdx.x & 255;      // row-chunk (RPB rows)
    const int cs   = cg * 4 + wave;         // 16-col strip id
    const int colstrip = cs * 16;

    // Weight prologue: 30 contiguous 1-KB loads.
    bf16x8 b[NMAT][2];
    const char* wbase = (const char*)wcs + (size_t)cs * 2048 + lane * 16;
#pragma unroll
    for (int w = 0; w < NMAT; ++w)
#pragma unroll
        for (int s = 0; s < 2; ++s)
            b[w][s] = *(const bf16x8*)(wbase + (size_t)w * 32768 + s * 1024);

    const f32x4 d0v = *(const f32x4*)(d0 + colstrip + g * 4);

    constexpr int OPS[NMAT] = {0,1,3,1,2,3,1,2,2,3,1,2,2,2,3};
    const size_t row0 = (size_t)rc * RPB;
    const char* xbase = (const char*)xs + (row0 >> 4) * 2048 + lane * 16;

    auto issue = [&](Tile& T, int t) {   // 4 contiguous 1-KB loads
        const char* p = xbase + (size_t)t * 4096;
        T.v00 = *(const bf16x8*)(p);
        T.v01 = *(const bf16x8*)(p + 1024);
        T.v10 = *(const bf16x8*)(p + 2048);
        T.v11 = *(const bf16x8*)(p + 3072);
    };

    auto cs_fn = [&](const Tile& U, int t) {
        f32x4 res0, res1, tmp0, tmp1;
        __builtin_amdgcn_s_setprio(1);
#pragma unroll
        for (int w = 0; w < NMAT; ++w) {
            f32x4 c0 = (OPS[w] == 0) ? d0v : f32x4{0.f, 0.f, 0.f, 0.f};
            f32x4 y0 = __builtin_amdgcn_mfma_f32_16x16x32_bf16(b[w][0], U.v00, c0, 0, 0, 0);
            y0       = __builtin_amdgcn_mfma_f32_16x16x32_bf16(b[w][1], U.v01, y0, 0, 0, 0);
            f32x4 y1 = __builtin_amdgcn_mfma_f32_16x16x32_bf16(b[w][0], U.v10, c0, 0, 0, 0);
            y1       = __builtin_amdgcn_mfma_f32_16x16x32_bf16(b[w][1], U.v11, y1, 0, 0, 0);
            if (OPS[w] == 0)      { res0 = y0; res1 = y1; }
            else if (OPS[w] == 1) { tmp0 = y0; tmp1 = y1; }
            else {
                tmp0 = tmp0 * y0; tmp1 = tmp1 * y1;
                if (OPS[w] == 3) { res0 = res0 + tmp0; res1 = res1 + tmp1; }
            }
        }
        __builtin_amdgcn_s_setprio(0);
        // LDS transpose (double-buffered): frag (row=l15/l15+16) -> [32][68]
        float* sb = sbuf[t & 1];
        const int colw = wave * 16 + g * 4;
        *(f32x4*)&sb[l15 * LDS_W + colw]        = res0;
        *(f32x4*)&sb[(16 + l15) * LDS_W + colw] = res1;
        // Raw barrier: wait ONLY on LDS (lgkm). Global prefetch loads and the
        // previous tile's stores stay in flight across the barrier (the
        // compiler's __syncthreads would drain vmcnt(0) here -> per-tile HBM
        // round-trip serialization). Buffer reuse safety: each wave's own
        // lgkmcnt(0) before barrier(t+1) guarantees its reads of buffer t are
        // complete before any wave reaches the t+2 write (one barrier later).
        asm volatile("s_waitcnt lgkmcnt(0)\n\ts_barrier" ::: "memory");
        // coalesced store: each wave-inst = 4 rows x 256 B (full lines)
        const size_t rbase = row0 + (size_t)t * 32;
#pragma unroll
        for (int j = 0; j < 2; ++j) {
            const int row = wave * 8 + j * 4 + g;
            f32x4 v = *(const f32x4*)&sb[row * LDS_W + l15 * 4];
            *(f32x4*)(out + (rbase + row) * OUTF + cg * 64 + l15 * 4) = v;
        }
    };

    Tile A, B;
    issue(A, 0); issue(B, 1);
    cs_fn(A, 0); issue(A, 2);
    cs_fn(B, 1); issue(B, 3);
    cs_fn(A, 2); issue(A, 4);
    cs_fn(B, 3); issue(B, 5);
    cs_fn(A, 4); issue(A, 6);
    cs_fn(B, 5); issue(B, 7);
    cs_fn(A, 6);
    cs_fn(B, 7);
}

// ---------------- fallback path (ws too small): R6-style fp32 kernel --------
__global__ void build_weights_only(const float* __restrict__ d1t_w,
                                   const float* __restrict__ d1_w,
                                   const float* __restrict__ dn_w1,
                                   const float* __restrict__ dn_w2,
                                   unsigned short* __restrict__ wc) {
    int idx = blockIdx.x * blockDim.x + threadIdx.x;
    if (idx >= NMAT * OUTF * INF) return;
    int slot = idx / (OUTF * INF);
    int rem  = idx - slot * (OUTF * INF);
    int i    = rem & (INF - 1);
    const signed char kind[NMAT] = {0,1,2,1,2,2,1,2,2,2,1,2,2,2,2};
    const signed char sidx[NMAT] = {0,0,0,1,1,2,2,3,4,5,3,6,7,8,9};
    int k = kind[slot], si = sidx[slot];
    float v;
    if (k == 0)      v = d1t_w[rem];
    else if (k == 1) v = d1_w[si * OUTF * INF + rem];
    else             v = dn_w2[si * OUTF * INF + rem] * dn_w1[si * INF + i];
    wc[idx] = f2bf(v);
}

__global__ __launch_bounds__(256) void taylor_f32(
    const float* __restrict__ x, const float* __restrict__ d0,
    const unsigned short* __restrict__ wc, float* __restrict__ out)
{
    const int lane = threadIdx.x & 63;
    const int wave = threadIdx.x >> 6;
    const int l15  = lane & 15;
    const int g    = lane >> 4;
    const int cg   = blockIdx.x & 3;
    const int rc   = blockIdx.x >> 2;
    const int colstrip = cg * 64 + wave * 16;

    bf16x8 b[NMAT][2];
#pragma unroll
    for (int w = 0; w < NMAT; ++w) {
        const unsigned short* wp = wc + ((size_t)w * OUTF + colstrip + l15) * INF + g * 8;
#pragma unroll
        for (int s = 0; s < 2; ++s)
            b[w][s] = *(const bf16x8*)(wp + s * 32);
    }
    const f32x4 d0v = *(const f32x4*)(d0 + colstrip + g * 4);
    constexpr int OPS[NMAT] = {0,1,3,1,2,3,1,2,2,3,1,2,2,2,3};
    const size_t row0 = (size_t)rc * RPB;

#pragma unroll 1
    for (int it = 0; it < RPB / 32; ++it) {
        bf16x8 a00, a01, a10, a11;
        {
            const float* xp0 = x + (row0 + (size_t)it * 32 + l15) * INF + g * 8;
            const float* xp1 = xp0 + 16 * INF;
            f32x4 u0, u1; bf16x8 fr;
#define CVT8(dst, p0) { u0 = *(const f32x4*)(p0); u1 = *(const f32x4*)((p0) + 4); \
            for (int j = 0; j < 4; ++j) { fr[j] = (__bf16)u0[j]; fr[4+j] = (__bf16)u1[j]; } dst = fr; }
            CVT8(a00, xp0); CVT8(a01, xp0 + 32); CVT8(a10, xp1); CVT8(a11, xp1 + 32);
#undef CVT8
        }
        f32x4 res0, res1, tmp0, tmp1;
#pragma unroll
        for (int w = 0; w < NMAT; ++w) {
            f32x4 c0 = (OPS[w] == 0) ? d0v : f32x4{0.f, 0.f, 0.f, 0.f};
            f32x4 y0 = __builtin_amdgcn_mfma_f32_16x16x32_bf16(b[w][0], a00, c0, 0, 0, 0);
            y0       = __builtin_amdgcn_mfma_f32_16x16x32_bf16(b[w][1], a01, y0, 0, 0, 0);
            f32x4 y1 = __builtin_amdgcn_mfma_f32_16x16x32_bf16(b[w][0], a10, c0, 0, 0, 0);
            y1       = __builtin_amdgcn_mfma_f32_16x16x32_bf16(b[w][1], a11, y1, 0, 0, 0);
            if (OPS[w] == 0)      { res0 = y0; res1 = y1; }
            else if (OPS[w] == 1) { tmp0 = y0; tmp1 = y1; }
            else {
                tmp0 = tmp0 * y0; tmp1 = tmp1 * y1;
                if (OPS[w] == 3) { res0 = res0 + tmp0; res1 = res1 + tmp1; }
            }
        }
        const size_t rbase = row0 + (size_t)it * 32;
        *(f32x4*)(out + (rbase + l15) * OUTF + colstrip + g * 4) = res0;
        *(f32x4*)(out + (rbase + 16 + l15) * OUTF + colstrip + g * 4) = res1;
    }
}

extern "C" void kernel_launch(void* const* d_in, const int* in_sizes, int n_in,
                              void* d_out, int out_size, void* d_ws, size_t ws_size,
                              hipStream_t stream) {
    const float* x    = (const float*)d_in[0];
    const float* d0   = (const float*)d_in[1];
    const float* d1t  = (const float*)d_in[2];
    const float* d1w  = (const float*)d_in[3];
    const float* dnw1 = (const float*)d_in[4];
    const float* dnw2 = (const float*)d_in[5];
    unsigned short* wc = (unsigned short*)d_ws;                 // 480 KiB (swizzled)
    float* out = (float*)d_out;

    const size_t XB_OFF   = 512 * 1024;
    const size_t XB_BYTES = (size_t)BATCH * INF * 2;            // 8 MiB
    if (ws_size >= XB_OFF + XB_BYTES) {
        unsigned short* xs = (unsigned short*)((char*)d_ws + XB_OFF);
        prep<<<BATCH * INF / 8 / 256, 256, 0, stream>>>(x, d1t, d1w, dnw1, dnw2, wc, xs);
        taylor_kernel<<<4 * (BATCH / RPB), 256, 0, stream>>>(xs, d0, wc, out);
    } else {
        build_weights_only<<<(NMAT * OUTF * INF + 255) / 256, 256, 0, stream>>>(d1t, d1w, dnw1, dnw2, wc);
        taylor_f32<<<4 * (BATCH / RPB), 256, 0, stream>>>(x, d0, wc, out);
    }
}